// Round 12
// baseline (662.792 us; speedup 1.0000x reference)
//
#include <hip/hip_runtime.h>
#include <math.h>

typedef unsigned int u32;
typedef unsigned long long u64;
typedef _Float16 half8 __attribute__((ext_vector_type(8)));
typedef float f32x4 __attribute__((ext_vector_type(4)));
typedef float f32x16 __attribute__((ext_vector_type(16)));

#define N_PIX 16384
#define N_ANC 147456
#define N_PRE 6000
#define TIE_BASE 6144
#define TIE_CAP  16384

// ws layout (bytes)
#define OFF_H      0ULL            // 16384*512*4 = 33554432
#define OFF_BOXES  33554432ULL     // 147456*16   = 2359296
#define OFF_KEYS   35913728ULL     // 147456*4    = 589824
#define OFF_W54    36503552ULL     // 131072
#define OFF_B54    36634624ULL     // 256
#define OFF_HIST1  36634880ULL     // 262144
#define OFF_HIST2  36897024ULL     // 262144
#define OFF_CTRL   37159168ULL     // 256
#define OFF_CAND   37159424ULL     // (6144+16384)*8 = 180224
#define OFF_SBOX   37339648ULL     // 6144*16 = 98304
#define OFF_MASK   37437952ULL     // 6016*94*8 = 4524032
#define BASE_NEEDED 41961984ULL
#define OFF_XH     41961984ULL     // 16777216 (fp16)
#define OFF_XL     58739200ULL     // 16777216
#define OFF_WHT    75516416ULL     // 4718592  (fp16, PK2 layout [nb][kb][ks][kh][n][8])
#define OFF_WLT    80235008ULL     // 4718592
#define FULL_NEEDED 84953600ULL

#define KEY_NEGINF 0x007FFFFFu     // flip(bits(-inf))

#define MASK_BYTES 4524032ULL      // 6016*94*8

struct AB { float v[36]; };

// ctrl: [0]=b1 [1]=A1 [2]=Kstar [3]=A [4]=need [5]=cntHigh [6]=cntTie [7]=L

// ---------------- prep device helpers ----------------
__device__ __forceinline__ void d_init_body(int i0, u32* hist1, u32* hist2, u32* ctrl, float* roi,
                       float* w54, float* b54,
                       const float* __restrict__ loc_w, const float* __restrict__ loc_b,
                       const float* __restrict__ score_w, const float* __restrict__ score_b) {
  const int stride = 256 * 256;
  const int TOT = 65536 * 2 + 64 + 1200 + 32768 + 64;
  for (int i = i0; i < TOT; i += stride) {
    if (i < 65536) hist1[i] = 0u;
    else if (i < 131072) hist2[i - 65536] = 0u;
    else if (i < 131136) ctrl[i - 131072] = 0u;
    else if (i < 132336) roi[i - 131136] = 0.f;
    else if (i < 165104) {
      int j = i - 132336;
      int k = j >> 6, oc = j & 63;
      float v = 0.f;
      if (oc < 36) v = loc_w[k * 36 + oc];
      else if (oc < 54) v = score_w[k * 18 + oc - 36];
      w54[(((k >> 2) << 6) + oc) * 4 + (k & 3)] = v;
    } else {
      int oc = i - 165104;
      float v = 0.f;
      if (oc < 36) v = loc_b[oc];
      else if (oc < 54) v = score_b[oc - 36];
      b54[oc] = v;
    }
  }
}

__device__ __forceinline__ void d_split_x_body(int b, int t, const float* __restrict__ x,
                                               _Float16* __restrict__ xh, _Float16* __restrict__ xl) {
  const int gid = b * 256 + t;
  const int base = gid << 3;
  float a[8];
  *(float4*)&a[0] = *(const float4*)(x + base);
  *(float4*)&a[4] = *(const float4*)(x + base + 4);
  half8 hh, ll;
#pragma unroll
  for (int j = 0; j < 8; ++j) {
    _Float16 hi = (_Float16)a[j];
    hh[j] = hi;
    ll[j] = (_Float16)((a[j] - (float)hi) * 2048.0f);
  }
  *(half8*)(xh + base) = hh;
  *(half8*)(xl + base) = ll;
}

// split + repack w -> PK2 layout: half index
//   ((((nb*144 + kb)*2 + ks)*2 + kh)*128 + n)*8 + j
// where kb = ci*9 + tap (tap-inner, matches conv K order), k-within-32 = ks*16 + kh*8 + j.
__device__ __forceinline__ void d_split_w_body(int kb64, int ob, int t, const float* __restrict__ w,
                                               _Float16* __restrict__ whPK, _Float16* __restrict__ wlPK,
                                               _Float16 (*th)[72], _Float16 (*tl)[72]) {
  {
    const int r = t >> 2, cq = t & 3;
    float a[16];
    const float* wp = w + ((size_t)(kb64 * 64 + r) << 9) + ob * 64 + cq * 16;
#pragma unroll
    for (int j = 0; j < 4; ++j) *(float4*)&a[j << 2] = *(const float4*)(wp + (j << 2));
    half8 h0, h1, l0, l1;
#pragma unroll
    for (int j = 0; j < 8; ++j) {
      _Float16 hi = (_Float16)a[j];
      h0[j] = hi; l0[j] = (_Float16)((a[j] - (float)hi) * 2048.0f);
    }
#pragma unroll
    for (int j = 0; j < 8; ++j) {
      _Float16 hi = (_Float16)a[8 + j];
      h1[j] = hi; l1[j] = (_Float16)((a[8 + j] - (float)hi) * 2048.0f);
    }
    *(half8*)&th[r][cq * 16]     = h0;
    *(half8*)&th[r][cq * 16 + 8] = h1;
    *(half8*)&tl[r][cq * 16]     = l0;
    *(half8*)&tl[r][cq * 16 + 8] = l1;
  }
  __syncthreads();
  {
    const int o_local = t & 63;
    const int hl = (t >> 6) & 1;
    const int cs = t >> 7;               // which 32-k half of this 64-row tile
    const int tap = kb64 >> 3;
    const int ci  = ((kb64 & 7) << 1) + cs;
    const int kb  = ci * 9 + tap;
    const int o   = ob * 64 + o_local;
    const int nb  = o >> 7, n = o & 127;
    _Float16* dst = (hl ? wlPK : whPK) + (((size_t)(nb * 144 + kb)) << 12) + n * 8;
    _Float16 (*src)[72] = hl ? tl : th;
    const int r0 = cs << 5;
#pragma unroll
    for (int q = 0; q < 4; ++q) {
      half8 v;
#pragma unroll
      for (int j = 0; j < 8; ++j) v[j] = src[r0 + (q << 3) + j][o_local];
      *(half8*)(dst + (q << 10)) = v;
    }
  }
}

// ---------------- init (fallback path) ----------------
__global__ void k_init(u32* hist1, u32* hist2, u32* ctrl, float* roi,
                       float* w54, float* b54,
                       const float* __restrict__ loc_w, const float* __restrict__ loc_b,
                       const float* __restrict__ score_w, const float* __restrict__ score_b) {
  const int i0 = blockIdx.x * blockDim.x + threadIdx.x;
  d_init_body(i0, hist1, hist2, ctrl, roi, w54, b54, loc_w, loc_b, score_w, score_b);
}

// ---------------- fused prep: split_x (4096) + split_w (576) + init (256) ----------------
__global__ __launch_bounds__(256) void k_prep(const float* __restrict__ x,
                                              _Float16* __restrict__ xh, _Float16* __restrict__ xl,
                                              const float* __restrict__ w,
                                              _Float16* __restrict__ whPK, _Float16* __restrict__ wlPK,
                                              u32* hist1, u32* hist2, u32* ctrl, float* roi,
                                              float* w54, float* b54,
                                              const float* __restrict__ loc_w, const float* __restrict__ loc_b,
                                              const float* __restrict__ score_w, const float* __restrict__ score_b) {
  __shared__ _Float16 th[64][72];
  __shared__ _Float16 tl[64][72];
  const int b = blockIdx.x;
  const int t = threadIdx.x;
  if (b < 4096) {
    d_split_x_body(b, t, x, xh, xl);
  } else if (b < 4672) {
    const int idx = b - 4096;
    d_split_w_body(idx % 72, idx / 72, t, w, whPK, wlPK, th, tl);
  } else {
    d_init_body((b - 4672) * 256 + t, hist1, hist2, ctrl, roi, w54, b54, loc_w, loc_b, score_w, score_b);
  }
}

// ---------------- conv (fast path): 32x32x16 MFMA, ci-slab LDS, px-split for occupancy ----------------
// r11 post-mortem: MFMA (1550cy) and LDS (1540cy) per tap-unit are co-critical but SUMMING
// (MfmaUtil 51%) because grid=512 caps at 2 waves/SIMD. Split each row into two 64-px
// halves: grid 1024, slab 66px=25.3KB, wave=64px x 32ch (acc 64 VGPR), launch_bounds(256,4)
// -> 4 blocks/CU, 4 waves/SIMD. Same totals per tap-unit; overlap turns sum into ~max.
// Accumulation sequence per output element unchanged -> bit-identical results.
__global__ __launch_bounds__(256, 4) void k_conv_pre(const _Float16* __restrict__ xh,
                                                     const _Float16* __restrict__ xl,
                                                     const _Float16* __restrict__ whPK,
                                                     const _Float16* __restrict__ wlPK,
                                                     const float* __restrict__ bias,
                                                     float* __restrict__ h) {
  __shared__ _Float16 As[2][3][4][66][8];   // 25,344 B  [hi/lo][ky][kq][px+halo][8]

  const int bid = blockIdx.x;
  const int q   = bid >> 3;                    // 0..127
  const int nb  = q >> 5;                      // 0..3
  const int r5  = q & 31;
  const int y   = ((bid & 7) << 4) + (r5 >> 1); // XCD gets contiguous 16-y band
  const int ph  = r5 & 1;
  const int px0 = ph << 6;                     // 0 or 64

  const int t  = threadIdx.x;
  const int wv = t >> 6, lane = t & 63;
  const int ln5 = lane & 31;
  const int kh  = lane >> 5;           // k-half within 16-k sub-step

  f32x16 acc_hh[2];
  f32x16 acc_x[2];
#pragma unroll
  for (int i = 0; i < 2; ++i) { acc_hh[i] = (f32x16)0.f; acc_x[i] = (f32x16)0.f; }

  // B per-lane const offset within a kb panel (halfs): kh*1024 + (wv*32+ln5)*8; +ks*2048
  const u32 wb = ((u32)kh << 10) + (((u32)((wv << 5) + ln5)) << 3);

  half8 bh0[2], bl0[2], bh1[2], bl1[2];  // B ping-pong [ks]

// stage the A-slab for channel-group CI: 1584 half8 chunks over 256 threads (7 iters)
#define STAGE(CI)                                                                \
  {                                                                              \
    const int ch0_ = (CI) << 5;                                                  \
    _Pragma("unroll")                                                            \
    for (int j_ = 0; j_ < 7; ++j_) {                                             \
      const int c_ = t + (j_ << 8);                                              \
      if (c_ < 1584) {                                                           \
        const int p_ = c_ % 66;                                                  \
        int r_ = c_ / 66;                                                        \
        const int kq_ = r_ & 3; r_ >>= 2;                                        \
        const int ky_ = r_ % 3; const int hl_ = r_ / 3;                          \
        const int yy_ = y + ky_ - 1, xx_ = px0 + p_ - 1;                         \
        half8 v_ = (half8)(_Float16)0;                                           \
        if (yy_ >= 0 && yy_ < 128 && xx_ >= 0 && xx_ < 128) {                    \
          const _Float16* sp_ = (hl_ ? xl : xh) +                                \
              ((((size_t)((yy_ << 7) + xx_)) << 9) + ch0_ + (kq_ << 3));         \
          v_ = *(const half8*)sp_;                                               \
        }                                                                        \
        *(half8*)As[hl_][ky_][kq_][p_] = v_;                                     \
      }                                                                          \
    }                                                                            \
  }

#define BLOAD(KB, BH, BL)                                                        \
  {                                                                              \
    const u32 kbase_ = ((u32)(nb * 144 + (KB))) << 12;   /* *4096 halfs/panel */ \
    _Pragma("unroll")                                                            \
    for (int ks_ = 0; ks_ < 2; ++ks_) {                                          \
      const u32 o_ = kbase_ + ((u32)ks_ << 11) + wb;                             \
      BH[ks_] = *(const half8*)(whPK + o_);                                      \
      BL[ks_] = *(const half8*)(wlPK + o_);                                      \
    }                                                                            \
  }

// frags from slab at runtime (KYv,KXv): 2 m-tiles x hi/lo, conflict-free
#define FRAGS2(KYv, KXv, KS, AH, AL)                                             \
  {                                                                              \
    const int kq_ = ((KS) << 1) + kh;                                            \
    _Pragma("unroll")                                                            \
    for (int mi = 0; mi < 2; ++mi) {                                             \
      AH[mi] = *(const half8*)As[0][KYv][kq_][(mi << 5) + ln5 + (KXv)];          \
      AL[mi] = *(const half8*)As[1][KYv][kq_][(mi << 5) + ln5 + (KXv)];          \
    }                                                                            \
  }

#define MFMA6(AH, AL, BH, BL, KS)                                                \
  {                                                                              \
    _Pragma("unroll")                                                            \
    for (int mi = 0; mi < 2; ++mi) {                                             \
      acc_hh[mi] = __builtin_amdgcn_mfma_f32_32x32x16_f16(AH[mi], BH[KS], acc_hh[mi], 0, 0, 0); \
      acc_x[mi]  = __builtin_amdgcn_mfma_f32_32x32x16_f16(AH[mi], BL[KS], acc_x[mi], 0, 0, 0);  \
      acc_x[mi]  = __builtin_amdgcn_mfma_f32_32x32x16_f16(AL[mi], BH[KS], acc_x[mi], 0, 0, 0);  \
    }                                                                            \
  }

#define LBARRIER()                                                               \
  {                                                                              \
    asm volatile("s_waitcnt lgkmcnt(0)" ::: "memory");                           \
    __builtin_amdgcn_s_barrier();                                                \
  }

// one tap step: frags, optional B prefetch into NXT, MFMA cluster (small-body shape)
#define TAPSTEP(KYv, KXv, CUR, CURL, DO_PF, PFKB, NXT, NXTL)                     \
  {                                                                              \
    half8 a0h[2], a0l[2];                                                        \
    FRAGS2(KYv, KXv, 0, a0h, a0l);                                               \
    if (DO_PF) { BLOAD(PFKB, NXT, NXTL); }                                       \
    __builtin_amdgcn_sched_barrier(0);                                           \
    __builtin_amdgcn_s_setprio(1);                                               \
    MFMA6(a0h, a0l, CUR, CURL, 0);                                               \
    __builtin_amdgcn_s_setprio(0);                                               \
    half8 a1h[2], a1l[2];                                                        \
    FRAGS2(KYv, KXv, 1, a1h, a1l);                                               \
    __builtin_amdgcn_s_setprio(1);                                               \
    MFMA6(a1h, a1l, CUR, CURL, 1);                                               \
    __builtin_amdgcn_s_setprio(0);                                               \
  }

  BLOAD(0, bh0, bl0);
  STAGE(0);
  LBARRIER();

#pragma unroll 1
  for (int ci = 0; ci < 16; ++ci) {
    const int kb0 = ci * 9;
#pragma unroll 1
    for (int jp = 0; jp < 4; ++jp) {
      const int tp  = jp << 1;
      const int ky0 = tp / 3,       kx0 = tp - ky0 * 3;
      const int ky1 = (tp + 1) / 3, kx1 = (tp + 1) - ky1 * 3;
      // even tap: compute with bh0, prefetch tap+1 -> bh1
      TAPSTEP(ky0, kx0, bh0, bl0, true, kb0 + tp + 1, bh1, bl1)
      // odd tap: compute with bh1, prefetch tap+2 (<=8) -> bh0
      TAPSTEP(ky1, kx1, bh1, bl1, true, kb0 + tp + 2, bh0, bl0)
    }
    // tap 8 (ky=2,kx=2): current in bh0; prefetch next group's tap0 -> bh1
    {
      const bool pf = (ci + 1 < 16);
      TAPSTEP(2, 2, bh0, bl0, pf, kb0 + 9, bh1, bl1)
    }
    if (ci + 1 < 16) {
      // restore parity: next group's tap0 operands into bh0
#pragma unroll
      for (int k_ = 0; k_ < 2; ++k_) {
        bh0[k_] = bh1[k_];
        bl0[k_] = bl1[k_];
      }
      LBARRIER();            // all waves done reading the slab
      STAGE(ci + 1);
      LBARRIER();            // slab ready
    }
  }
#undef STAGE
#undef BLOAD
#undef FRAGS2
#undef MFMA6
#undef LBARRIER
#undef TAPSTEP

  // epilogue: 32x32 C layout: col = lane&31, row = (r&3) + 8*(r>>2) + 4*(lane>>5)
  const float inv2048 = 1.0f / 2048.0f;
  const int colg = (nb << 7) + (wv << 5) + ln5;
  const float bbv = bias[colg];
#pragma unroll
  for (int mi = 0; mi < 2; ++mi) {
#pragma unroll
    for (int r = 0; r < 16; ++r) {
      const int row = px0 + (mi << 5) + (r & 3) + ((r >> 2) << 3) + (kh << 2);
      float v = acc_hh[mi][r] + acc_x[mi][r] * inv2048 + bbv;
      h[(((size_t)((y << 7) + row)) << 9) + colg] = fmaxf(v, 0.f);
    }
  }
}

// ---------------- conv (fallback): in-kernel split ----------------
#define APAD 40
__global__ __launch_bounds__(256, 2) void k_conv_fb(const float* __restrict__ x,
                                                    const float* __restrict__ w,
                                                    const float* __restrict__ bias,
                                                    float* __restrict__ h) {
  __shared__ _Float16 Ah[128][APAD];
  __shared__ _Float16 Al[128][APAD];
  __shared__ _Float16 Bh[128][APAD];
  __shared__ _Float16 Bl[128][APAD];

  const int y  = blockIdx.x;
  const int nb = blockIdx.y;
  const int t  = threadIdx.x;
  const int wv = t >> 6, lane = t & 63;
  const int m0 = (wv >> 1) << 6;
  const int n0 = (wv & 1) << 6;
  const int fm = lane & 15;
  const int fq = lane >> 4;
  const int sa_m = t >> 1;
  const int sa_h = (t & 1) << 4;
  const int sb_n = t & 127;
  const int sb_kg = (t >> 7) << 4;

  f32x4 acc_hh[4][4];
  f32x4 acc_x[4][4];
#pragma unroll
  for (int i = 0; i < 4; ++i)
#pragma unroll
    for (int j = 0; j < 4; ++j) { acc_hh[i][j] = (f32x4)0.f; acc_x[i][j] = (f32x4)0.f; }

#pragma unroll 1
  for (int kb = 0; kb < 144; ++kb) {
    const int tap  = kb >> 4;
    const int ky   = tap / 3, kx = tap - ky * 3;
    const int cin0 = (kb & 15) << 5;
    {
      const int yy = y + ky - 1;
      const int xx = sa_m + kx - 1;
      float av[16];
      if (yy >= 0 && yy < 128 && xx >= 0 && xx < 128) {
        const float* ap = x + (((size_t)((yy << 7) + xx)) << 9) + cin0 + sa_h;
#pragma unroll
        for (int j = 0; j < 4; ++j) *(float4*)&av[j << 2] = *(const float4*)(ap + (j << 2));
      } else {
#pragma unroll
        for (int j = 0; j < 16; ++j) av[j] = 0.f;
      }
      half8 h0, h1, l0, l1;
#pragma unroll
      for (int j = 0; j < 8; ++j) {
        _Float16 hi = (_Float16)av[j];
        h0[j] = hi; l0[j] = (_Float16)((av[j] - (float)hi) * 2048.0f);
      }
#pragma unroll
      for (int j = 0; j < 8; ++j) {
        _Float16 hi = (_Float16)av[8 + j];
        h1[j] = hi; l1[j] = (_Float16)((av[8 + j] - (float)hi) * 2048.0f);
      }
      *(half8*)&Ah[sa_m][sa_h]     = h0;
      *(half8*)&Ah[sa_m][sa_h + 8] = h1;
      *(half8*)&Al[sa_m][sa_h]     = l0;
      *(half8*)&Al[sa_m][sa_h + 8] = l1;
    }
    {
      const float* bp = w + ((size_t)(tap * 512 + cin0 + sb_kg) << 9) + (nb << 7) + sb_n;
      float bv[16];
#pragma unroll
      for (int j = 0; j < 16; ++j) bv[j] = bp[(size_t)j << 9];
      half8 h0, h1, l0, l1;
#pragma unroll
      for (int j = 0; j < 8; ++j) {
        _Float16 hi = (_Float16)bv[j];
        h0[j] = hi; l0[j] = (_Float16)((bv[j] - (float)hi) * 2048.0f);
      }
#pragma unroll
      for (int j = 0; j < 8; ++j) {
        _Float16 hi = (_Float16)bv[8 + j];
        h1[j] = hi; l1[j] = (_Float16)((bv[8 + j] - (float)hi) * 2048.0f);
      }
      *(half8*)&Bh[sb_n][sb_kg]     = h0;
      *(half8*)&Bh[sb_n][sb_kg + 8] = h1;
      *(half8*)&Bl[sb_n][sb_kg]     = l0;
      *(half8*)&Bl[sb_n][sb_kg + 8] = l1;
    }
    __syncthreads();
    half8 ah[4], al[4], bh[4], bl[4];
#pragma unroll
    for (int i = 0; i < 4; ++i) {
      ah[i] = *(const half8*)&Ah[m0 + (i << 4) + fm][fq << 3];
      al[i] = *(const half8*)&Al[m0 + (i << 4) + fm][fq << 3];
      bh[i] = *(const half8*)&Bh[n0 + (i << 4) + fm][fq << 3];
      bl[i] = *(const half8*)&Bl[n0 + (i << 4) + fm][fq << 3];
    }
#pragma unroll
    for (int mi = 0; mi < 4; ++mi)
#pragma unroll
      for (int ni = 0; ni < 4; ++ni) {
        acc_hh[mi][ni] = __builtin_amdgcn_mfma_f32_16x16x32_f16(ah[mi], bh[ni], acc_hh[mi][ni], 0, 0, 0);
        acc_x[mi][ni]  = __builtin_amdgcn_mfma_f32_16x16x32_f16(ah[mi], bl[ni], acc_x[mi][ni], 0, 0, 0);
        acc_x[mi][ni]  = __builtin_amdgcn_mfma_f32_16x16x32_f16(al[mi], bh[ni], acc_x[mi][ni], 0, 0, 0);
      }
    __syncthreads();
  }
  const float inv2048 = 1.0f / 2048.0f;
#pragma unroll
  for (int mi = 0; mi < 4; ++mi)
#pragma unroll
    for (int ni = 0; ni < 4; ++ni) {
      const int col = n0 + (ni << 4) + fm;
      const float bb = bias[(nb << 7) + col];
#pragma unroll
      for (int r = 0; r < 4; ++r) {
        const int row = m0 + (mi << 4) + (fq << 2) + r;
        float v = acc_hh[mi][ni][r] + acc_x[mi][ni][r] * inv2048 + bb;
        h[(((size_t)((y << 7) + row)) << 9) + (nb << 7) + col] = fmaxf(v, 0.f);
      }
    }
}

// ---------------- heads (+ hist1 fold) ----------------
__global__ __launch_bounds__(256) void k_heads(const float* __restrict__ h,
        const float4* __restrict__ w54, const float* __restrict__ b54,
        float* __restrict__ out0, float* __restrict__ out1, float* __restrict__ out3,
        float4* __restrict__ boxes, u32* __restrict__ keys, u32* __restrict__ hist1,
        const int* __restrict__ p_ih, const int* __restrict__ p_iw,
        const int* __restrict__ p_sc, AB ab) {
  __shared__ float hl[16 * 512];
  __shared__ float vals[16][64];
  const int t = threadIdx.x;
  const int wv = t >> 6, lane = t & 63;
  const int pbase = blockIdx.x << 4;

#pragma unroll
  for (int j = 0; j < 8; ++j) {
    const int f = (j << 8) + t;
    ((float4*)hl)[f] = ((const float4*)(h + ((size_t)pbase << 9)))[f];
  }
  __syncthreads();

  const float* hp = hl + ((wv << 2) << 9);
  float a0 = 0.f, a1 = 0.f, a2 = 0.f, a3 = 0.f;
#pragma unroll 4
  for (int kq = 0; kq < 128; ++kq) {
    const float4 wvv = w54[(kq << 6) + lane];
    const float4 h0 = *(const float4*)(hp + (kq << 2));
    const float4 h1 = *(const float4*)(hp + 512 + (kq << 2));
    const float4 h2 = *(const float4*)(hp + 1024 + (kq << 2));
    const float4 h3 = *(const float4*)(hp + 1536 + (kq << 2));
    a0 += h0.x * wvv.x + h0.y * wvv.y + h0.z * wvv.z + h0.w * wvv.w;
    a1 += h1.x * wvv.x + h1.y * wvv.y + h1.z * wvv.z + h1.w * wvv.w;
    a2 += h2.x * wvv.x + h2.y * wvv.y + h2.z * wvv.z + h2.w * wvv.w;
    a3 += h3.x * wvv.x + h3.y * wvv.y + h3.z * wvv.z + h3.w * wvv.w;
  }
  const float bb = b54[lane];
  float av[4] = {a0 + bb, a1 + bb, a2 + bb, a3 + bb};
#pragma unroll
  for (int px = 0; px < 4; ++px) {
    const int p = pbase + (wv << 2) + px;
    vals[(wv << 2) + px][lane] = av[px];
    if (lane < 36) out0[p * 36 + lane] = av[px];
    else if (lane < 54) out1[p * 18 + lane - 36] = av[px];
  }
  __syncthreads();

  if (lane < 36) {
    const int px = lane / 9, a = lane - px * 9;
    const int p = pbase + (wv << 2) + px;
    const float* vv = vals[(wv << 2) + px];
    const float l0 = vv[(a << 2) + 0], l1 = vv[(a << 2) + 1];
    const float l2 = vv[(a << 2) + 2], l3 = vv[(a << 2) + 3];
    const float s0 = vv[36 + (a << 1)], s1 = vv[37 + (a << 1)];
    const int yq = p >> 7, xq = p & 127;
    const float fy = (float)(yq << 4), fx = (float)(xq << 4);
    const float ay1 = ab.v[(a << 2) + 0] + fy;
    const float ax1 = ab.v[(a << 2) + 1] + fx;
    const float ay2 = ab.v[(a << 2) + 2] + fy;
    const float ax2 = ab.v[(a << 2) + 3] + fx;
    const int idx = p * 9 + a;
    *(float4*)(out3 + ((size_t)idx << 2)) = make_float4(ay1, ax1, ay2, ax2);

    const float sh = ay2 - ay1, sw = ax2 - ax1;
    const float scy = ay1 + 0.5f * sh, scx = ax1 + 0.5f * sw;
    const float cy = l0 * sh + scy, cx = l1 * sw + scx;
    const float bh = expf(l2) * sh, bw = expf(l3) * sw;
    const float IH = (float)p_ih[0], IW = (float)p_iw[0];
    float d0 = fminf(fmaxf(cy - 0.5f * bh, 0.f), IH);
    float d1 = fminf(fmaxf(cx - 0.5f * bw, 0.f), IW);
    float d2 = fminf(fmaxf(cy + 0.5f * bh, 0.f), IH);
    float d3 = fminf(fmaxf(cx + 0.5f * bw, 0.f), IW);
    boxes[idx] = make_float4(d0, d1, d2, d3);

    const float minsz = 16.f * (float)p_sc[0];
    const bool keep = (d2 - d0 >= minsz) && (d3 - d1 >= minsz);
    const float mx = fmaxf(s0, s1);
    const float e0 = expf(s0 - mx), e1 = expf(s1 - mx);
    const float fg = e1 / (e0 + e1);
    const float sc = keep ? fg : -INFINITY;
    const u32 u = __float_as_uint(sc);
    const u32 key = (u & 0x80000000u) ? ~u : (u | 0x80000000u);
    keys[idx] = key;
    atomicAdd(&hist1[key >> 16], 1u);
  }
}

// ---------------- top-6000: two-level radix select ----------------
__global__ void k_hist2(const u32* __restrict__ keys, const u32* __restrict__ ctrl,
                        u32* __restrict__ hist2) {
  const u32 b1 = ctrl[0];
  int i = blockIdx.x * blockDim.x + threadIdx.x;
  if (i < N_ANC) {
    const u32 k = keys[i];
    if ((k >> 16) == b1) atomicAdd(&hist2[k & 0xFFFFu], 1u);
  }
}

__global__ __launch_bounds__(1024) void k_findcut(const u32* __restrict__ hist,
                                                  u32* __restrict__ ctrl, int mode) {
  __shared__ u32 csum[1024];
  __shared__ u32 suf[1024];
  const int t = threadIdx.x;
  const u32 target = (mode == 0) ? (u32)N_PRE : ((u32)N_PRE - ctrl[1]);
  const int base = t << 6;
  u32 s = 0;
  for (int i = 0; i < 64; ++i) s += hist[base + i];
  csum[t] = s;
  suf[t] = s;
  __syncthreads();
  for (int off = 1; off < 1024; off <<= 1) {
    u32 add = (t + off < 1024) ? suf[t + off] : 0u;
    __syncthreads();
    suf[t] += add;
    __syncthreads();
  }
  const u32 excl = suf[t] - csum[t];
  if (excl < target && target <= suf[t]) {
    u32 cum = excl;
    int bkt = base;
    for (int i = 63; i >= 0; --i) {
      const u32 hh = hist[base + i];
      if (cum < target && target <= cum + hh) { bkt = base + i; break; }
      cum += hh;
    }
    if (mode == 0) { ctrl[0] = (u32)bkt; ctrl[1] = cum; }
    else {
      const u32 Kstar = (ctrl[0] << 16) | (u32)bkt;
      const u32 A = ctrl[1] + cum;
      u32 need = (u32)N_PRE - A;
      if (Kstar == KEY_NEGINF) need = 0u;
      ctrl[2] = Kstar; ctrl[3] = A; ctrl[4] = need;
      ctrl[7] = A + need;   // L
    }
  }
}

__global__ void k_compact(const u32* __restrict__ keys, u32* __restrict__ ctrl,
                          u64* __restrict__ cand) {
  const u32 Kstar = ctrl[2];
  const u32 need  = ctrl[4];
  int i = blockIdx.x * blockDim.x + threadIdx.x;
  if (i >= N_ANC) return;
  const u32 k = keys[i];
  if (k > Kstar) {
    const u32 pos = atomicAdd(&ctrl[5], 1u);
    cand[pos] = ((u64)k << 32) | (u64)(u32)(~(u32)i);
  } else if (k == Kstar && need != 0u) {
    const u32 pos = atomicAdd(&ctrl[6], 1u);
    if (pos < (u32)TIE_CAP) cand[TIE_BASE + pos] = ((u64)Kstar << 32) | (u64)(u32)(~(u32)i);
  }
}

// rank-placement sort: sbox[rank(v_i)] = boxes[idx(v_i)] for rank < L.
// grid-stride over candidates (grid 8192; C <= 6000 + ties normally -> one pass)
__global__ __launch_bounds__(128) void k_rank(const u32* __restrict__ ctrl,
                                              const u64* __restrict__ cand,
                                              const float4* __restrict__ boxes,
                                              float4* __restrict__ sbox) {
  __shared__ u32 wred[2];
  const u32 A   = ctrl[3];
  const u32 tcc = min(ctrl[6], (u32)TIE_CAP);
  const u32 C   = A + tcc;
  const u32 L   = ctrl[7];
  const int t   = threadIdx.x;
  for (u32 i = blockIdx.x; i < C; i += gridDim.x) {
    const u64 v = (i < A) ? cand[i] : cand[TIE_BASE + (i - A)];
    u32 cnt = 0;
    for (u32 j = t; j < A; j += 128) cnt += (cand[j] > v);
    for (u32 j = t; j < tcc; j += 128) cnt += (cand[TIE_BASE + j] > v);
#pragma unroll
    for (int off = 32; off > 0; off >>= 1) cnt += __shfl_xor(cnt, off);
    if ((t & 63) == 0) wred[t >> 6] = cnt;
    __syncthreads();
    if (t == 0) {
      const u32 rank = wred[0] + wred[1];
      if (rank < L) {
        const u32 idx = ~((u32)(v & 0xFFFFFFFFULL));
        sbox[rank] = boxes[idx];
      }
    }
    __syncthreads();
  }
}

// ---------------- NMS ----------------
// 256-thread blocks: 4 col-words per block (one per wave); grid (24, 94)
__global__ __launch_bounds__(256) void k_mask(const u32* __restrict__ ctrl,
                                              const float4* __restrict__ sbox,
                                              u64* __restrict__ mask) {
  const int L = (int)ctrl[7];
  const int rb = blockIdx.y;       // row block 0..93
  if (rb * 64 >= L) return;
  const int wv = threadIdx.x >> 6;
  const int lane = threadIdx.x & 63;
  const int cw = (blockIdx.x << 2) + wv;   // col word
  if (cw > 93 || cw < rb) return;  // lower-triangle words never pass above-mask filter
  const int j = cw * 64 + lane;
  const bool jok = (j < L);
  const float4 cb = jok ? sbox[j] : make_float4(0.f, 0.f, 0.f, 0.f);
  const float careaJ = (cb.z - cb.x) * (cb.w - cb.y);
  const int rbase = rb * 64;
  const float4 rbx = (rbase + lane < L) ? sbox[rbase + lane] : make_float4(0.f, 0.f, 0.f, 0.f);
  const int rmax = min(64, L - rbase);
  for (int r = 0; r < rmax; ++r) {
    const float ry1 = __shfl(rbx.x, r), rx1 = __shfl(rbx.y, r);
    const float ry2 = __shfl(rbx.z, r), rx2 = __shfl(rbx.w, r);
    const float ra = (ry2 - ry1) * (rx2 - rx1);
    const float iy1 = fmaxf(cb.x, ry1), ix1 = fmaxf(cb.y, rx1);
    const float iy2 = fminf(cb.z, ry2), ix2 = fminf(cb.w, rx2);
    const float inter = fmaxf(iy2 - iy1, 0.f) * fmaxf(ix2 - ix1, 0.f);
    const float iou = inter / (careaJ + ra - inter + 1e-9f);
    const bool bit = jok && (iou > 0.7f);
    const u64 bal = __ballot(bit);
    if (lane == 0) mask[(size_t)(rbase + r) * 94 + cw] = bal;
  }
}

__device__ inline u64 valid_mask_fn(int base, int L) {
  const int r = L - base;
  if (r <= 0) return 0ULL;
  if (r >= 64) return ~0ULL;
  return (1ULL << r) - 1ULL;
}
__device__ inline u64 above_mask_fn(int base, int i) {
  if (i < base) return ~0ULL;
  const int s = i - base + 1;
  if (s >= 64) return 0ULL;
  return (~0ULL) << s;
}

__device__ __forceinline__ void gload_lds16(const void* g, void* l) {
  __builtin_amdgcn_global_load_lds(
      (const __attribute__((address_space(1))) void*)g,
      (__attribute__((address_space(3))) void*)l, 16, 0, 0);
}

// Demand-paged LDS greedy NMS: issue 16-row batches (12 x 1KB global_load_lds) on demand
// around the current selection row, 4-slot rotation, counted vmcnt. Skipped batches are
// never issued. Argmin via uniform ballot+ctz+shfl instead of 6-step shfl_xor chain.
__global__ __launch_bounds__(64) void k_greedy(const u32* __restrict__ ctrl,
                                               const float* __restrict__ sboxf,
                                               const u64* __restrict__ mask,
                                               float* __restrict__ roi) {
  __shared__ char lds[4 * 12288];
  const int lane = threadIdx.x;
  const int L = (int)ctrl[7];
  if (L <= 0) return;
  const char* gmask = (const char*)mask;
  const char* gend  = gmask + MASK_BYTES;
  const int nbatch = (L + 15) >> 4;

#define GISSUE(BB)                                                         \
  {                                                                        \
    const char* gb_ = gmask + (size_t)(BB) * 12032;                        \
    char* lb_ = lds + ((BB) & 3) * 12288;                                  \
    _Pragma("unroll")                                                      \
    for (int j_ = 0; j_ < 12; ++j_) {                                      \
      const char* ga_ = gb_ + j_ * 1024;                                   \
      if (ga_ + 1024 > gend) ga_ = gend - 1024;   /* clamp: pads rows>=6000 only */ \
      gload_lds16(ga_ + lane * 16, lb_ + j_ * 1024);                       \
    }                                                                      \
  }

  int next_issue = 0;
  int ready = -1;
  const int base0 = lane << 6;
  const int base1 = (64 + lane) << 6;
  const u64 v0 = valid_mask_fn(base0, L);
  const u64 v1 = (lane < 30) ? valid_mask_fn(base1, L) : 0ULL;
  u64 rem0 = 0ULL, rem1 = 0ULL;
  int i = 0, kept = 0;

  while (i >= 0 && kept < 300) {
    const int bi = i >> 4;
    if (bi > ready) {
      if (next_issue < bi) next_issue = bi;      // skip never-needed batches
      const int want = min(bi + 3, nbatch - 1);
      while (next_issue <= want) { GISSUE(next_issue); ++next_issue; }
      const int out = next_issue - 1 - bi;       // batches issued after bi
      if (out >= 3)      asm volatile("s_waitcnt vmcnt(36)" ::: "memory");
      else if (out == 2) asm volatile("s_waitcnt vmcnt(24)" ::: "memory");
      else if (out == 1) asm volatile("s_waitcnt vmcnt(12)" ::: "memory");
      else               asm volatile("s_waitcnt vmcnt(0)"  ::: "memory");
      ready = bi;
    }
    if (lane < 4) roi[kept * 4 + lane] = sboxf[(size_t)i * 4 + lane];
    ++kept;
    const u64* rowp = (const u64*)(lds + (bi & 3) * 12288 + (i & 15) * 752);
    rem0 |= rowp[lane];
    if (lane < 30) rem1 |= rowp[64 + lane];
    const u64 f0 = ~rem0 & v0 & above_mask_fn(base0, i);
    const u64 f1 = ~rem1 & v1 & above_mask_fn(base1, i);
    int ni = -1;
    const u64 b0 = __ballot(f0 != 0ULL);
    if (b0) {
      const int w = (int)__builtin_ctzll(b0);
      const u64 fw = (u64)__shfl((long long)f0, w);
      ni = (w << 6) + (int)__builtin_ctzll(fw);
    } else {
      const u64 b1m = __ballot(f1 != 0ULL);
      if (b1m) {
        const int w = (int)__builtin_ctzll(b1m);
        const u64 fw = (u64)__shfl((long long)f1, w);
        ni = ((64 + w) << 6) + (int)__builtin_ctzll(fw);
      }
    }
    i = ni;
  }
#undef GISSUE
}

// ---------------- launch ----------------
extern "C" void kernel_launch(void* const* d_in, const int* in_sizes, int n_in,
                              void* d_out, int out_size, void* d_ws, size_t ws_size,
                              hipStream_t stream) {
  (void)in_sizes; (void)n_in; (void)out_size;
  if (ws_size < BASE_NEEDED) return;
  const bool fast = (ws_size >= FULL_NEEDED);

  const float* x       = (const float*)d_in[0];
  const float* conv_w  = (const float*)d_in[1];
  const float* conv_b  = (const float*)d_in[2];
  const float* loc_w   = (const float*)d_in[3];
  const float* loc_b   = (const float*)d_in[4];
  const float* score_w = (const float*)d_in[5];
  const float* score_b = (const float*)d_in[6];
  const int* p_ih = (const int*)d_in[7];
  const int* p_iw = (const int*)d_in[8];
  const int* p_sc = (const int*)d_in[9];

  float* out0 = (float*)d_out;
  float* out1 = out0 + 589824;
  float* roi  = out1 + 294912;
  float* out3 = roi + 1200;

  char* ws = (char*)d_ws;
  float*     h     = (float*)(ws + OFF_H);
  float4*    boxes = (float4*)(ws + OFF_BOXES);
  u32*       keys  = (u32*)(ws + OFF_KEYS);
  float*     w54   = (float*)(ws + OFF_W54);
  float*     b54   = (float*)(ws + OFF_B54);
  u32*       hist1 = (u32*)(ws + OFF_HIST1);
  u32*       hist2 = (u32*)(ws + OFF_HIST2);
  u32*       ctrl  = (u32*)(ws + OFF_CTRL);
  u64*       cand  = (u64*)(ws + OFF_CAND);
  float4*    sbox  = (float4*)(ws + OFF_SBOX);
  u64*       mask  = (u64*)(ws + OFF_MASK);
  _Float16*  xh    = (_Float16*)(ws + OFF_XH);
  _Float16*  xl    = (_Float16*)(ws + OFF_XL);
  _Float16*  whPK  = (_Float16*)(ws + OFF_WHT);
  _Float16*  wlPK  = (_Float16*)(ws + OFF_WLT);

  AB ab;
  {
    const double ratios[3] = {0.5, 1.0, 2.0};
    const double scales[3] = {8.0, 16.0, 32.0};
    for (int i = 0; i < 3; ++i)
      for (int j = 0; j < 3; ++j) {
        const double hh = 16.0 * scales[j] * sqrt(ratios[i]);
        const double wwv = 16.0 * scales[j] * sqrt(1.0 / ratios[i]);
        const int a = i * 3 + j;
        ab.v[a * 4 + 0] = (float)(8.0 - hh / 2.0);
        ab.v[a * 4 + 1] = (float)(8.0 - wwv / 2.0);
        ab.v[a * 4 + 2] = (float)(8.0 + hh / 2.0);
        ab.v[a * 4 + 3] = (float)(8.0 + wwv / 2.0);
      }
  }

  if (fast) {
    hipLaunchKernelGGL(k_prep, dim3(4928), dim3(256), 0, stream,
                       x, xh, xl, conv_w, whPK, wlPK,
                       hist1, hist2, ctrl, roi, w54, b54, loc_w, loc_b, score_w, score_b);
    hipLaunchKernelGGL(k_conv_pre, dim3(1024), dim3(256), 0, stream, xh, xl, whPK, wlPK, conv_b, h);
  } else {
    hipLaunchKernelGGL(k_init, dim3(256), dim3(256), 0, stream,
                       hist1, hist2, ctrl, roi, w54, b54, loc_w, loc_b, score_w, score_b);
    hipLaunchKernelGGL(k_conv_fb, dim3(128, 4), dim3(256), 0, stream, x, conv_w, conv_b, h);
  }
  hipLaunchKernelGGL(k_heads, dim3(1024), dim3(256), 0, stream,
                     h, (const float4*)w54, b54, out0, out1, out3, boxes, keys, hist1,
                     p_ih, p_iw, p_sc, ab);
  hipLaunchKernelGGL(k_findcut, dim3(1), dim3(1024), 0, stream, hist1, ctrl, 0);
  hipLaunchKernelGGL(k_hist2, dim3(576), dim3(256), 0, stream, keys, ctrl, hist2);
  hipLaunchKernelGGL(k_findcut, dim3(1), dim3(1024), 0, stream, hist2, ctrl, 1);
  hipLaunchKernelGGL(k_compact, dim3(576), dim3(256), 0, stream, keys, ctrl, cand);
  hipLaunchKernelGGL(k_rank, dim3(8192), dim3(128), 0, stream, ctrl, cand, boxes, sbox);
  hipLaunchKernelGGL(k_mask, dim3(24, 94), dim3(256), 0, stream, ctrl, sbox, mask);
  hipLaunchKernelGGL(k_greedy, dim3(1), dim3(64), 0, stream, ctrl, (const float*)sbox, mask, roi);
}

// Round 13
// 624.414 us; speedup vs baseline: 1.0615x; 1.0615x over previous
//
#include <hip/hip_runtime.h>
#include <math.h>

typedef unsigned int u32;
typedef unsigned long long u64;
typedef _Float16 half8 __attribute__((ext_vector_type(8)));
typedef float f32x4 __attribute__((ext_vector_type(4)));
typedef float f32x16 __attribute__((ext_vector_type(16)));

#define N_PIX 16384
#define N_ANC 147456
#define N_PRE 6000
#define TIE_BASE 6144
#define TIE_CAP  16384

// ws layout (bytes)
#define OFF_H      0ULL            // 16384*512*4 = 33554432
#define OFF_BOXES  33554432ULL     // 147456*16   = 2359296
#define OFF_KEYS   35913728ULL     // 147456*4    = 589824
#define OFF_W54    36503552ULL     // 131072
#define OFF_B54    36634624ULL     // 256
#define OFF_HIST1  36634880ULL     // 262144
#define OFF_HIST2  36897024ULL     // 262144
#define OFF_CTRL   37159168ULL     // 256
#define OFF_CAND   37159424ULL     // (6144+16384)*8 = 180224
#define OFF_SBOX   37339648ULL     // 6144*16 = 98304
#define OFF_MASK   37437952ULL     // 6016*94*8 = 4524032
#define BASE_NEEDED 41961984ULL
#define OFF_XH     41961984ULL     // 16777216 (fp16)
#define OFF_XL     58739200ULL     // 16777216
#define OFF_WHT    75516416ULL     // 4718592  (fp16, PK2 layout [nb][kb][ks][kh][n][8])
#define OFF_WLT    80235008ULL     // 4718592
#define FULL_NEEDED 84953600ULL

#define KEY_NEGINF 0x007FFFFFu     // flip(bits(-inf))

#define MASK_BYTES 4524032ULL      // 6016*94*8

struct AB { float v[36]; };

// ctrl: [0]=b1 [1]=A1 [2]=Kstar [3]=A [4]=need [5]=cntHigh [6]=cntTie [7]=L

// ---------------- prep device helpers ----------------
__device__ __forceinline__ void d_init_body(int i0, u32* hist1, u32* hist2, u32* ctrl, float* roi,
                       float* w54, float* b54,
                       const float* __restrict__ loc_w, const float* __restrict__ loc_b,
                       const float* __restrict__ score_w, const float* __restrict__ score_b) {
  const int stride = 256 * 256;
  const int TOT = 65536 * 2 + 64 + 1200 + 32768 + 64;
  for (int i = i0; i < TOT; i += stride) {
    if (i < 65536) hist1[i] = 0u;
    else if (i < 131072) hist2[i - 65536] = 0u;
    else if (i < 131136) ctrl[i - 131072] = 0u;
    else if (i < 132336) roi[i - 131136] = 0.f;
    else if (i < 165104) {
      int j = i - 132336;
      int k = j >> 6, oc = j & 63;
      float v = 0.f;
      if (oc < 36) v = loc_w[k * 36 + oc];
      else if (oc < 54) v = score_w[k * 18 + oc - 36];
      w54[(((k >> 2) << 6) + oc) * 4 + (k & 3)] = v;
    } else {
      int oc = i - 165104;
      float v = 0.f;
      if (oc < 36) v = loc_b[oc];
      else if (oc < 54) v = score_b[oc - 36];
      b54[oc] = v;
    }
  }
}

__device__ __forceinline__ void d_split_x_body(int b, int t, const float* __restrict__ x,
                                               _Float16* __restrict__ xh, _Float16* __restrict__ xl) {
  const int gid = b * 256 + t;
  const int base = gid << 3;
  float a[8];
  *(float4*)&a[0] = *(const float4*)(x + base);
  *(float4*)&a[4] = *(const float4*)(x + base + 4);
  half8 hh, ll;
#pragma unroll
  for (int j = 0; j < 8; ++j) {
    _Float16 hi = (_Float16)a[j];
    hh[j] = hi;
    ll[j] = (_Float16)((a[j] - (float)hi) * 2048.0f);
  }
  *(half8*)(xh + base) = hh;
  *(half8*)(xl + base) = ll;
}

// split + repack w -> PK2 layout: half index
//   ((((nb*144 + kb)*2 + ks)*2 + kh)*128 + n)*8 + j
// where kb = ci*9 + tap (tap-inner, matches conv K order), k-within-32 = ks*16 + kh*8 + j.
__device__ __forceinline__ void d_split_w_body(int kb64, int ob, int t, const float* __restrict__ w,
                                               _Float16* __restrict__ whPK, _Float16* __restrict__ wlPK,
                                               _Float16 (*th)[72], _Float16 (*tl)[72]) {
  {
    const int r = t >> 2, cq = t & 3;
    float a[16];
    const float* wp = w + ((size_t)(kb64 * 64 + r) << 9) + ob * 64 + cq * 16;
#pragma unroll
    for (int j = 0; j < 4; ++j) *(float4*)&a[j << 2] = *(const float4*)(wp + (j << 2));
    half8 h0, h1, l0, l1;
#pragma unroll
    for (int j = 0; j < 8; ++j) {
      _Float16 hi = (_Float16)a[j];
      h0[j] = hi; l0[j] = (_Float16)((a[j] - (float)hi) * 2048.0f);
    }
#pragma unroll
    for (int j = 0; j < 8; ++j) {
      _Float16 hi = (_Float16)a[8 + j];
      h1[j] = hi; l1[j] = (_Float16)((a[8 + j] - (float)hi) * 2048.0f);
    }
    *(half8*)&th[r][cq * 16]     = h0;
    *(half8*)&th[r][cq * 16 + 8] = h1;
    *(half8*)&tl[r][cq * 16]     = l0;
    *(half8*)&tl[r][cq * 16 + 8] = l1;
  }
  __syncthreads();
  {
    const int o_local = t & 63;
    const int hl = (t >> 6) & 1;
    const int cs = t >> 7;               // which 32-k half of this 64-row tile
    const int tap = kb64 >> 3;
    const int ci  = ((kb64 & 7) << 1) + cs;
    const int kb  = ci * 9 + tap;
    const int o   = ob * 64 + o_local;
    const int nb  = o >> 7, n = o & 127;
    _Float16* dst = (hl ? wlPK : whPK) + (((size_t)(nb * 144 + kb)) << 12) + n * 8;
    _Float16 (*src)[72] = hl ? tl : th;
    const int r0 = cs << 5;
#pragma unroll
    for (int q = 0; q < 4; ++q) {
      half8 v;
#pragma unroll
      for (int j = 0; j < 8; ++j) v[j] = src[r0 + (q << 3) + j][o_local];
      *(half8*)(dst + (q << 10)) = v;
    }
  }
}

// ---------------- init (fallback path) ----------------
__global__ void k_init(u32* hist1, u32* hist2, u32* ctrl, float* roi,
                       float* w54, float* b54,
                       const float* __restrict__ loc_w, const float* __restrict__ loc_b,
                       const float* __restrict__ score_w, const float* __restrict__ score_b) {
  const int i0 = blockIdx.x * blockDim.x + threadIdx.x;
  d_init_body(i0, hist1, hist2, ctrl, roi, w54, b54, loc_w, loc_b, score_w, score_b);
}

// ---------------- fused prep: split_x (4096) + split_w (576) + init (256) ----------------
__global__ __launch_bounds__(256) void k_prep(const float* __restrict__ x,
                                              _Float16* __restrict__ xh, _Float16* __restrict__ xl,
                                              const float* __restrict__ w,
                                              _Float16* __restrict__ whPK, _Float16* __restrict__ wlPK,
                                              u32* hist1, u32* hist2, u32* ctrl, float* roi,
                                              float* w54, float* b54,
                                              const float* __restrict__ loc_w, const float* __restrict__ loc_b,
                                              const float* __restrict__ score_w, const float* __restrict__ score_b) {
  __shared__ _Float16 th[64][72];
  __shared__ _Float16 tl[64][72];
  const int b = blockIdx.x;
  const int t = threadIdx.x;
  if (b < 4096) {
    d_split_x_body(b, t, x, xh, xl);
  } else if (b < 4672) {
    const int idx = b - 4096;
    d_split_w_body(idx % 72, idx / 72, t, w, whPK, wlPK, th, tl);
  } else {
    d_init_body((b - 4672) * 256 + t, hist1, hist2, ctrl, roi, w54, b54, loc_w, loc_b, score_w, score_b);
  }
}

// ---------------- conv (fast path): 32x32x16 MFMA, ci-slab LDS, 128px x 32ch waves ----------------
// Measured-best conv configuration (r11): grid 512, slab 130px = 49.9KB, wave = 128px x 32ch
// (M_rep=4, N_rep=1), B per-lane from PK2-packed global, reg ping-pong; zero bank conflicts;
// 230us @ MfmaUtil 51%. r12's px-split occupancy experiment regressed (cache pressure);
// this is the plateau of the 3-term hi/lo MFMA scheme (floor ~97us).
__global__ __launch_bounds__(256, 2) void k_conv_pre(const _Float16* __restrict__ xh,
                                                     const _Float16* __restrict__ xl,
                                                     const _Float16* __restrict__ whPK,
                                                     const _Float16* __restrict__ wlPK,
                                                     const float* __restrict__ bias,
                                                     float* __restrict__ h) {
  __shared__ _Float16 As[2][3][4][130][8];   // 49,920 B  [hi/lo][ky][kq][px+halo][8]

  const int bid = blockIdx.x;
  const int q   = bid >> 3;                    // 0..63
  const int nb  = q >> 4;                      // 0..3
  const int y   = ((bid & 7) << 4) + (q & 15); // XCD gets contiguous 16-y band

  const int t  = threadIdx.x;
  const int wv = t >> 6, lane = t & 63;
  const int ln5 = lane & 31;
  const int kh  = lane >> 5;           // k-half within 16-k sub-step

  f32x16 acc_hh[4];
  f32x16 acc_x[4];
#pragma unroll
  for (int i = 0; i < 4; ++i) { acc_hh[i] = (f32x16)0.f; acc_x[i] = (f32x16)0.f; }

  // B per-lane const offset within a kb panel (halfs): kh*1024 + (wv*32+ln5)*8; +ks*2048
  const u32 wb = ((u32)kh << 10) + (((u32)((wv << 5) + ln5)) << 3);

  half8 bh0[2], bl0[2], bh1[2], bl1[2];  // B ping-pong [ks]

// stage the A-slab for channel-group CI: 3120 half8 chunks over 256 threads (13 iters)
#define STAGE(CI)                                                                \
  {                                                                              \
    const int ch0_ = (CI) << 5;                                                  \
    _Pragma("unroll")                                                            \
    for (int j_ = 0; j_ < 13; ++j_) {                                            \
      const int c_ = t + (j_ << 8);                                              \
      if (c_ < 3120) {                                                           \
        const int p_ = c_ % 130;                                                 \
        int r_ = c_ / 130;                                                       \
        const int kq_ = r_ & 3; r_ >>= 2;                                        \
        const int ky_ = r_ % 3; const int hl_ = r_ / 3;                          \
        const int yy_ = y + ky_ - 1, xx_ = p_ - 1;                               \
        half8 v_ = (half8)(_Float16)0;                                           \
        if (yy_ >= 0 && yy_ < 128 && xx_ >= 0 && xx_ < 128) {                    \
          const _Float16* sp_ = (hl_ ? xl : xh) +                                \
              ((((size_t)((yy_ << 7) + xx_)) << 9) + ch0_ + (kq_ << 3));         \
          v_ = *(const half8*)sp_;                                               \
        }                                                                        \
        *(half8*)As[hl_][ky_][kq_][p_] = v_;                                     \
      }                                                                          \
    }                                                                            \
  }

#define BLOAD(KB, BH, BL)                                                        \
  {                                                                              \
    const u32 kbase_ = ((u32)(nb * 144 + (KB))) << 12;   /* *4096 halfs/panel */ \
    _Pragma("unroll")                                                            \
    for (int ks_ = 0; ks_ < 2; ++ks_) {                                          \
      const u32 o_ = kbase_ + ((u32)ks_ << 11) + wb;                             \
      BH[ks_] = *(const half8*)(whPK + o_);                                      \
      BL[ks_] = *(const half8*)(wlPK + o_);                                      \
    }                                                                            \
  }

// frags from slab at runtime (KYv,KXv): 4 m-tiles x hi/lo, conflict-free
#define FRAGS2(KYv, KXv, KS, AH, AL)                                             \
  {                                                                              \
    const int kq_ = ((KS) << 1) + kh;                                            \
    _Pragma("unroll")                                                            \
    for (int mi = 0; mi < 4; ++mi) {                                             \
      AH[mi] = *(const half8*)As[0][KYv][kq_][(mi << 5) + ln5 + (KXv)];          \
      AL[mi] = *(const half8*)As[1][KYv][kq_][(mi << 5) + ln5 + (KXv)];          \
    }                                                                            \
  }

#define MFMA12(AH, AL, BH, BL, KS)                                               \
  {                                                                              \
    _Pragma("unroll")                                                            \
    for (int mi = 0; mi < 4; ++mi) {                                             \
      acc_hh[mi] = __builtin_amdgcn_mfma_f32_32x32x16_f16(AH[mi], BH[KS], acc_hh[mi], 0, 0, 0); \
      acc_x[mi]  = __builtin_amdgcn_mfma_f32_32x32x16_f16(AH[mi], BL[KS], acc_x[mi], 0, 0, 0);  \
      acc_x[mi]  = __builtin_amdgcn_mfma_f32_32x32x16_f16(AL[mi], BH[KS], acc_x[mi], 0, 0, 0);  \
    }                                                                            \
  }

#define LBARRIER()                                                               \
  {                                                                              \
    asm volatile("s_waitcnt lgkmcnt(0)" ::: "memory");                           \
    __builtin_amdgcn_s_barrier();                                                \
  }

// one tap step: frags, optional B prefetch into NXT, MFMA cluster (small-body shape)
#define TAPSTEP(KYv, KXv, CUR, CURL, DO_PF, PFKB, NXT, NXTL)                     \
  {                                                                              \
    half8 a0h[4], a0l[4];                                                        \
    FRAGS2(KYv, KXv, 0, a0h, a0l);                                               \
    if (DO_PF) { BLOAD(PFKB, NXT, NXTL); }                                       \
    __builtin_amdgcn_sched_barrier(0);                                           \
    __builtin_amdgcn_s_setprio(1);                                               \
    MFMA12(a0h, a0l, CUR, CURL, 0);                                              \
    __builtin_amdgcn_s_setprio(0);                                               \
    half8 a1h[4], a1l[4];                                                        \
    FRAGS2(KYv, KXv, 1, a1h, a1l);                                               \
    __builtin_amdgcn_s_setprio(1);                                               \
    MFMA12(a1h, a1l, CUR, CURL, 1);                                              \
    __builtin_amdgcn_s_setprio(0);                                               \
  }

  BLOAD(0, bh0, bl0);
  STAGE(0);
  LBARRIER();

#pragma unroll 1
  for (int ci = 0; ci < 16; ++ci) {
    const int kb0 = ci * 9;
#pragma unroll 1
    for (int jp = 0; jp < 4; ++jp) {
      const int tp  = jp << 1;
      const int ky0 = tp / 3,       kx0 = tp - ky0 * 3;
      const int ky1 = (tp + 1) / 3, kx1 = (tp + 1) - ky1 * 3;
      // even tap: compute with bh0, prefetch tap+1 -> bh1
      TAPSTEP(ky0, kx0, bh0, bl0, true, kb0 + tp + 1, bh1, bl1)
      // odd tap: compute with bh1, prefetch tap+2 (<=8) -> bh0
      TAPSTEP(ky1, kx1, bh1, bl1, true, kb0 + tp + 2, bh0, bl0)
    }
    // tap 8 (ky=2,kx=2): current in bh0; prefetch next group's tap0 -> bh1
    {
      const bool pf = (ci + 1 < 16);
      TAPSTEP(2, 2, bh0, bl0, pf, kb0 + 9, bh1, bl1)
    }
    if (ci + 1 < 16) {
      // restore parity: next group's tap0 operands into bh0
#pragma unroll
      for (int k_ = 0; k_ < 2; ++k_) {
        bh0[k_] = bh1[k_];
        bl0[k_] = bl1[k_];
      }
      LBARRIER();            // all waves done reading the slab
      STAGE(ci + 1);
      LBARRIER();            // slab ready
    }
  }
#undef STAGE
#undef BLOAD
#undef FRAGS2
#undef MFMA12
#undef LBARRIER
#undef TAPSTEP

  // epilogue: 32x32 C layout: col = lane&31, row = (r&3) + 8*(r>>2) + 4*(lane>>5)
  const float inv2048 = 1.0f / 2048.0f;
  const int colg = (nb << 7) + (wv << 5) + ln5;
  const float bbv = bias[colg];
#pragma unroll
  for (int mi = 0; mi < 4; ++mi) {
#pragma unroll
    for (int r = 0; r < 16; ++r) {
      const int row = (mi << 5) + (r & 3) + ((r >> 2) << 3) + (kh << 2);
      float v = acc_hh[mi][r] + acc_x[mi][r] * inv2048 + bbv;
      h[(((size_t)((y << 7) + row)) << 9) + colg] = fmaxf(v, 0.f);
    }
  }
}

// ---------------- conv (fallback): in-kernel split ----------------
#define APAD 40
__global__ __launch_bounds__(256, 2) void k_conv_fb(const float* __restrict__ x,
                                                    const float* __restrict__ w,
                                                    const float* __restrict__ bias,
                                                    float* __restrict__ h) {
  __shared__ _Float16 Ah[128][APAD];
  __shared__ _Float16 Al[128][APAD];
  __shared__ _Float16 Bh[128][APAD];
  __shared__ _Float16 Bl[128][APAD];

  const int y  = blockIdx.x;
  const int nb = blockIdx.y;
  const int t  = threadIdx.x;
  const int wv = t >> 6, lane = t & 63;
  const int m0 = (wv >> 1) << 6;
  const int n0 = (wv & 1) << 6;
  const int fm = lane & 15;
  const int fq = lane >> 4;
  const int sa_m = t >> 1;
  const int sa_h = (t & 1) << 4;
  const int sb_n = t & 127;
  const int sb_kg = (t >> 7) << 4;

  f32x4 acc_hh[4][4];
  f32x4 acc_x[4][4];
#pragma unroll
  for (int i = 0; i < 4; ++i)
#pragma unroll
    for (int j = 0; j < 4; ++j) { acc_hh[i][j] = (f32x4)0.f; acc_x[i][j] = (f32x4)0.f; }

#pragma unroll 1
  for (int kb = 0; kb < 144; ++kb) {
    const int tap  = kb >> 4;
    const int ky   = tap / 3, kx = tap - ky * 3;
    const int cin0 = (kb & 15) << 5;
    {
      const int yy = y + ky - 1;
      const int xx = sa_m + kx - 1;
      float av[16];
      if (yy >= 0 && yy < 128 && xx >= 0 && xx < 128) {
        const float* ap = x + (((size_t)((yy << 7) + xx)) << 9) + cin0 + sa_h;
#pragma unroll
        for (int j = 0; j < 4; ++j) *(float4*)&av[j << 2] = *(const float4*)(ap + (j << 2));
      } else {
#pragma unroll
        for (int j = 0; j < 16; ++j) av[j] = 0.f;
      }
      half8 h0, h1, l0, l1;
#pragma unroll
      for (int j = 0; j < 8; ++j) {
        _Float16 hi = (_Float16)av[j];
        h0[j] = hi; l0[j] = (_Float16)((av[j] - (float)hi) * 2048.0f);
      }
#pragma unroll
      for (int j = 0; j < 8; ++j) {
        _Float16 hi = (_Float16)av[8 + j];
        h1[j] = hi; l1[j] = (_Float16)((av[8 + j] - (float)hi) * 2048.0f);
      }
      *(half8*)&Ah[sa_m][sa_h]     = h0;
      *(half8*)&Ah[sa_m][sa_h + 8] = h1;
      *(half8*)&Al[sa_m][sa_h]     = l0;
      *(half8*)&Al[sa_m][sa_h + 8] = l1;
    }
    {
      const float* bp = w + ((size_t)(tap * 512 + cin0 + sb_kg) << 9) + (nb << 7) + sb_n;
      float bv[16];
#pragma unroll
      for (int j = 0; j < 16; ++j) bv[j] = bp[(size_t)j << 9];
      half8 h0, h1, l0, l1;
#pragma unroll
      for (int j = 0; j < 8; ++j) {
        _Float16 hi = (_Float16)bv[j];
        h0[j] = hi; l0[j] = (_Float16)((bv[j] - (float)hi) * 2048.0f);
      }
#pragma unroll
      for (int j = 0; j < 8; ++j) {
        _Float16 hi = (_Float16)bv[8 + j];
        h1[j] = hi; l1[j] = (_Float16)((bv[8 + j] - (float)hi) * 2048.0f);
      }
      *(half8*)&Bh[sb_n][sb_kg]     = h0;
      *(half8*)&Bh[sb_n][sb_kg + 8] = h1;
      *(half8*)&Bl[sb_n][sb_kg]     = l0;
      *(half8*)&Bl[sb_n][sb_kg + 8] = l1;
    }
    __syncthreads();
    half8 ah[4], al[4], bh[4], bl[4];
#pragma unroll
    for (int i = 0; i < 4; ++i) {
      ah[i] = *(const half8*)&Ah[m0 + (i << 4) + fm][fq << 3];
      al[i] = *(const half8*)&Al[m0 + (i << 4) + fm][fq << 3];
      bh[i] = *(const half8*)&Bh[n0 + (i << 4) + fm][fq << 3];
      bl[i] = *(const half8*)&Bl[n0 + (i << 4) + fm][fq << 3];
    }
#pragma unroll
    for (int mi = 0; mi < 4; ++mi)
#pragma unroll
      for (int ni = 0; ni < 4; ++ni) {
        acc_hh[mi][ni] = __builtin_amdgcn_mfma_f32_16x16x32_f16(ah[mi], bh[ni], acc_hh[mi][ni], 0, 0, 0);
        acc_x[mi][ni]  = __builtin_amdgcn_mfma_f32_16x16x32_f16(ah[mi], bl[ni], acc_x[mi][ni], 0, 0, 0);
        acc_x[mi][ni]  = __builtin_amdgcn_mfma_f32_16x16x32_f16(al[mi], bh[ni], acc_x[mi][ni], 0, 0, 0);
      }
    __syncthreads();
  }
  const float inv2048 = 1.0f / 2048.0f;
#pragma unroll
  for (int mi = 0; mi < 4; ++mi)
#pragma unroll
    for (int ni = 0; ni < 4; ++ni) {
      const int col = n0 + (ni << 4) + fm;
      const float bb = bias[(nb << 7) + col];
#pragma unroll
      for (int r = 0; r < 4; ++r) {
        const int row = m0 + (mi << 4) + (fq << 2) + r;
        float v = acc_hh[mi][ni][r] + acc_x[mi][ni][r] * inv2048 + bb;
        h[(((size_t)((y << 7) + row)) << 9) + (nb << 7) + col] = fmaxf(v, 0.f);
      }
    }
}

// ---------------- heads (+ hist1 fold) ----------------
__global__ __launch_bounds__(256) void k_heads(const float* __restrict__ h,
        const float4* __restrict__ w54, const float* __restrict__ b54,
        float* __restrict__ out0, float* __restrict__ out1, float* __restrict__ out3,
        float4* __restrict__ boxes, u32* __restrict__ keys, u32* __restrict__ hist1,
        const int* __restrict__ p_ih, const int* __restrict__ p_iw,
        const int* __restrict__ p_sc, AB ab) {
  __shared__ float hl[16 * 512];
  __shared__ float vals[16][64];
  const int t = threadIdx.x;
  const int wv = t >> 6, lane = t & 63;
  const int pbase = blockIdx.x << 4;

#pragma unroll
  for (int j = 0; j < 8; ++j) {
    const int f = (j << 8) + t;
    ((float4*)hl)[f] = ((const float4*)(h + ((size_t)pbase << 9)))[f];
  }
  __syncthreads();

  const float* hp = hl + ((wv << 2) << 9);
  float a0 = 0.f, a1 = 0.f, a2 = 0.f, a3 = 0.f;
#pragma unroll 4
  for (int kq = 0; kq < 128; ++kq) {
    const float4 wvv = w54[(kq << 6) + lane];
    const float4 h0 = *(const float4*)(hp + (kq << 2));
    const float4 h1 = *(const float4*)(hp + 512 + (kq << 2));
    const float4 h2 = *(const float4*)(hp + 1024 + (kq << 2));
    const float4 h3 = *(const float4*)(hp + 1536 + (kq << 2));
    a0 += h0.x * wvv.x + h0.y * wvv.y + h0.z * wvv.z + h0.w * wvv.w;
    a1 += h1.x * wvv.x + h1.y * wvv.y + h1.z * wvv.z + h1.w * wvv.w;
    a2 += h2.x * wvv.x + h2.y * wvv.y + h2.z * wvv.z + h2.w * wvv.w;
    a3 += h3.x * wvv.x + h3.y * wvv.y + h3.z * wvv.z + h3.w * wvv.w;
  }
  const float bb = b54[lane];
  float av[4] = {a0 + bb, a1 + bb, a2 + bb, a3 + bb};
#pragma unroll
  for (int px = 0; px < 4; ++px) {
    const int p = pbase + (wv << 2) + px;
    vals[(wv << 2) + px][lane] = av[px];
    if (lane < 36) out0[p * 36 + lane] = av[px];
    else if (lane < 54) out1[p * 18 + lane - 36] = av[px];
  }
  __syncthreads();

  if (lane < 36) {
    const int px = lane / 9, a = lane - px * 9;
    const int p = pbase + (wv << 2) + px;
    const float* vv = vals[(wv << 2) + px];
    const float l0 = vv[(a << 2) + 0], l1 = vv[(a << 2) + 1];
    const float l2 = vv[(a << 2) + 2], l3 = vv[(a << 2) + 3];
    const float s0 = vv[36 + (a << 1)], s1 = vv[37 + (a << 1)];
    const int yq = p >> 7, xq = p & 127;
    const float fy = (float)(yq << 4), fx = (float)(xq << 4);
    const float ay1 = ab.v[(a << 2) + 0] + fy;
    const float ax1 = ab.v[(a << 2) + 1] + fx;
    const float ay2 = ab.v[(a << 2) + 2] + fy;
    const float ax2 = ab.v[(a << 2) + 3] + fx;
    const int idx = p * 9 + a;
    *(float4*)(out3 + ((size_t)idx << 2)) = make_float4(ay1, ax1, ay2, ax2);

    const float sh = ay2 - ay1, sw = ax2 - ax1;
    const float scy = ay1 + 0.5f * sh, scx = ax1 + 0.5f * sw;
    const float cy = l0 * sh + scy, cx = l1 * sw + scx;
    const float bh = expf(l2) * sh, bw = expf(l3) * sw;
    const float IH = (float)p_ih[0], IW = (float)p_iw[0];
    float d0 = fminf(fmaxf(cy - 0.5f * bh, 0.f), IH);
    float d1 = fminf(fmaxf(cx - 0.5f * bw, 0.f), IW);
    float d2 = fminf(fmaxf(cy + 0.5f * bh, 0.f), IH);
    float d3 = fminf(fmaxf(cx + 0.5f * bw, 0.f), IW);
    boxes[idx] = make_float4(d0, d1, d2, d3);

    const float minsz = 16.f * (float)p_sc[0];
    const bool keep = (d2 - d0 >= minsz) && (d3 - d1 >= minsz);
    const float mx = fmaxf(s0, s1);
    const float e0 = expf(s0 - mx), e1 = expf(s1 - mx);
    const float fg = e1 / (e0 + e1);
    const float sc = keep ? fg : -INFINITY;
    const u32 u = __float_as_uint(sc);
    const u32 key = (u & 0x80000000u) ? ~u : (u | 0x80000000u);
    keys[idx] = key;
    atomicAdd(&hist1[key >> 16], 1u);
  }
}

// ---------------- top-6000: two-level radix select ----------------
__global__ void k_hist2(const u32* __restrict__ keys, const u32* __restrict__ ctrl,
                        u32* __restrict__ hist2) {
  const u32 b1 = ctrl[0];
  int i = blockIdx.x * blockDim.x + threadIdx.x;
  if (i < N_ANC) {
    const u32 k = keys[i];
    if ((k >> 16) == b1) atomicAdd(&hist2[k & 0xFFFFu], 1u);
  }
}

__global__ __launch_bounds__(1024) void k_findcut(const u32* __restrict__ hist,
                                                  u32* __restrict__ ctrl, int mode) {
  __shared__ u32 csum[1024];
  __shared__ u32 suf[1024];
  const int t = threadIdx.x;
  const u32 target = (mode == 0) ? (u32)N_PRE : ((u32)N_PRE - ctrl[1]);
  const int base = t << 6;
  u32 s = 0;
  for (int i = 0; i < 64; ++i) s += hist[base + i];
  csum[t] = s;
  suf[t] = s;
  __syncthreads();
  for (int off = 1; off < 1024; off <<= 1) {
    u32 add = (t + off < 1024) ? suf[t + off] : 0u;
    __syncthreads();
    suf[t] += add;
    __syncthreads();
  }
  const u32 excl = suf[t] - csum[t];
  if (excl < target && target <= suf[t]) {
    u32 cum = excl;
    int bkt = base;
    for (int i = 63; i >= 0; --i) {
      const u32 hh = hist[base + i];
      if (cum < target && target <= cum + hh) { bkt = base + i; break; }
      cum += hh;
    }
    if (mode == 0) { ctrl[0] = (u32)bkt; ctrl[1] = cum; }
    else {
      const u32 Kstar = (ctrl[0] << 16) | (u32)bkt;
      const u32 A = ctrl[1] + cum;
      u32 need = (u32)N_PRE - A;
      if (Kstar == KEY_NEGINF) need = 0u;
      ctrl[2] = Kstar; ctrl[3] = A; ctrl[4] = need;
      ctrl[7] = A + need;   // L
    }
  }
}

__global__ void k_compact(const u32* __restrict__ keys, u32* __restrict__ ctrl,
                          u64* __restrict__ cand) {
  const u32 Kstar = ctrl[2];
  const u32 need  = ctrl[4];
  int i = blockIdx.x * blockDim.x + threadIdx.x;
  if (i >= N_ANC) return;
  const u32 k = keys[i];
  if (k > Kstar) {
    const u32 pos = atomicAdd(&ctrl[5], 1u);
    cand[pos] = ((u64)k << 32) | (u64)(u32)(~(u32)i);
  } else if (k == Kstar && need != 0u) {
    const u32 pos = atomicAdd(&ctrl[6], 1u);
    if (pos < (u32)TIE_CAP) cand[TIE_BASE + pos] = ((u64)Kstar << 32) | (u64)(u32)(~(u32)i);
  }
}

// rank-placement sort: sbox[rank(v_i)] = boxes[idx(v_i)] for rank < L.
// grid-stride over candidates (grid 8192; C <= 6000 + ties normally -> one pass)
__global__ __launch_bounds__(128) void k_rank(const u32* __restrict__ ctrl,
                                              const u64* __restrict__ cand,
                                              const float4* __restrict__ boxes,
                                              float4* __restrict__ sbox) {
  __shared__ u32 wred[2];
  const u32 A   = ctrl[3];
  const u32 tcc = min(ctrl[6], (u32)TIE_CAP);
  const u32 C   = A + tcc;
  const u32 L   = ctrl[7];
  const int t   = threadIdx.x;
  for (u32 i = blockIdx.x; i < C; i += gridDim.x) {
    const u64 v = (i < A) ? cand[i] : cand[TIE_BASE + (i - A)];
    u32 cnt = 0;
    for (u32 j = t; j < A; j += 128) cnt += (cand[j] > v);
    for (u32 j = t; j < tcc; j += 128) cnt += (cand[TIE_BASE + j] > v);
#pragma unroll
    for (int off = 32; off > 0; off >>= 1) cnt += __shfl_xor(cnt, off);
    if ((t & 63) == 0) wred[t >> 6] = cnt;
    __syncthreads();
    if (t == 0) {
      const u32 rank = wred[0] + wred[1];
      if (rank < L) {
        const u32 idx = ~((u32)(v & 0xFFFFFFFFULL));
        sbox[rank] = boxes[idx];
      }
    }
    __syncthreads();
  }
}

// ---------------- NMS ----------------
// 256-thread blocks: 4 col-words per block (one per wave); grid (24, 94)
__global__ __launch_bounds__(256) void k_mask(const u32* __restrict__ ctrl,
                                              const float4* __restrict__ sbox,
                                              u64* __restrict__ mask) {
  const int L = (int)ctrl[7];
  const int rb = blockIdx.y;       // row block 0..93
  if (rb * 64 >= L) return;
  const int wv = threadIdx.x >> 6;
  const int lane = threadIdx.x & 63;
  const int cw = (blockIdx.x << 2) + wv;   // col word
  if (cw > 93 || cw < rb) return;  // lower-triangle words never pass above-mask filter
  const int j = cw * 64 + lane;
  const bool jok = (j < L);
  const float4 cb = jok ? sbox[j] : make_float4(0.f, 0.f, 0.f, 0.f);
  const float careaJ = (cb.z - cb.x) * (cb.w - cb.y);
  const int rbase = rb * 64;
  const float4 rbx = (rbase + lane < L) ? sbox[rbase + lane] : make_float4(0.f, 0.f, 0.f, 0.f);
  const int rmax = min(64, L - rbase);
  for (int r = 0; r < rmax; ++r) {
    const float ry1 = __shfl(rbx.x, r), rx1 = __shfl(rbx.y, r);
    const float ry2 = __shfl(rbx.z, r), rx2 = __shfl(rbx.w, r);
    const float ra = (ry2 - ry1) * (rx2 - rx1);
    const float iy1 = fmaxf(cb.x, ry1), ix1 = fmaxf(cb.y, rx1);
    const float iy2 = fminf(cb.z, ry2), ix2 = fminf(cb.w, rx2);
    const float inter = fmaxf(iy2 - iy1, 0.f) * fmaxf(ix2 - ix1, 0.f);
    const float iou = inter / (careaJ + ra - inter + 1e-9f);
    const bool bit = jok && (iou > 0.7f);
    const u64 bal = __ballot(bit);
    if (lane == 0) mask[(size_t)(rbase + r) * 94 + cw] = bal;
  }
}

__device__ inline u64 valid_mask_fn(int base, int L) {
  const int r = L - base;
  if (r <= 0) return 0ULL;
  if (r >= 64) return ~0ULL;
  return (1ULL << r) - 1ULL;
}
__device__ inline u64 above_mask_fn(int base, int i) {
  if (i < base) return ~0ULL;
  const int s = i - base + 1;
  if (s >= 64) return 0ULL;
  return (~0ULL) << s;
}

__device__ __forceinline__ void gload_lds16(const void* g, void* l) {
  __builtin_amdgcn_global_load_lds(
      (const __attribute__((address_space(1))) void*)g,
      (__attribute__((address_space(3))) void*)l, 16, 0, 0);
}

// Demand-paged LDS greedy NMS + full sbox preload into LDS (96KB; the per-iteration
// dependent sbox read was ~250cy L2 on the serial critical path -> now ~120cy LDS).
// Mask rows stream through a 4-slot LDS rotation with counted vmcnt; skipped batches
// never issued; ballot/ctz argmin.
__global__ __launch_bounds__(64) void k_greedy(const u32* __restrict__ ctrl,
                                               const float* __restrict__ sboxf,
                                               const u64* __restrict__ mask,
                                               float* __restrict__ roi) {
  __shared__ char lds[4 * 12288];        // 49,152 B mask slots
  __shared__ float sbl[6144 * 4];        // 98,304 B sbox copy (total 147,456 <= 160K)
  const int lane = threadIdx.x;
  const int L = (int)ctrl[7];
  if (L <= 0) return;
  const char* gmask = (const char*)mask;
  const char* gend  = gmask + MASK_BYTES;
  const int nbatch = (L + 15) >> 4;

  // preload all of sbox into LDS: 96 x 1KB chunks; completion forced by the first
  // counted vmcnt wait below (in-order retirement: these are oldest in the queue).
#pragma unroll 1
  for (int j = 0; j < 96; ++j)
    gload_lds16((const char*)sboxf + j * 1024 + lane * 16, (char*)sbl + j * 1024);

#define GISSUE(BB)                                                         \
  {                                                                        \
    const char* gb_ = gmask + (size_t)(BB) * 12032;                        \
    char* lb_ = lds + ((BB) & 3) * 12288;                                  \
    _Pragma("unroll")                                                      \
    for (int j_ = 0; j_ < 12; ++j_) {                                      \
      const char* ga_ = gb_ + j_ * 1024;                                   \
      if (ga_ + 1024 > gend) ga_ = gend - 1024;   /* clamp: pads rows>=6000 only */ \
      gload_lds16(ga_ + lane * 16, lb_ + j_ * 1024);                       \
    }                                                                      \
  }

  int next_issue = 0;
  int ready = -1;
  const int base0 = lane << 6;
  const int base1 = (64 + lane) << 6;
  const u64 v0 = valid_mask_fn(base0, L);
  const u64 v1 = (lane < 30) ? valid_mask_fn(base1, L) : 0ULL;
  u64 rem0 = 0ULL, rem1 = 0ULL;
  int i = 0, kept = 0;

  while (i >= 0 && kept < 300) {
    const int bi = i >> 4;
    if (bi > ready) {
      if (next_issue < bi) next_issue = bi;      // skip never-needed batches
      const int want = min(bi + 3, nbatch - 1);
      while (next_issue <= want) { GISSUE(next_issue); ++next_issue; }
      const int out = next_issue - 1 - bi;       // batches issued after bi
      // wait until only the post-bi batches' loads remain outstanding; older
      // loads (sbox preload, earlier batches) retire first -> conservative
      if (out >= 3)      asm volatile("s_waitcnt vmcnt(36)" ::: "memory");
      else if (out == 2) asm volatile("s_waitcnt vmcnt(24)" ::: "memory");
      else if (out == 1) asm volatile("s_waitcnt vmcnt(12)" ::: "memory");
      else               asm volatile("s_waitcnt vmcnt(0)"  ::: "memory");
      ready = bi;
    }
    if (lane < 4) roi[kept * 4 + lane] = sbl[(i << 2) + lane];
    ++kept;
    const u64* rowp = (const u64*)(lds + (bi & 3) * 12288 + (i & 15) * 752);
    rem0 |= rowp[lane];
    if (lane < 30) rem1 |= rowp[64 + lane];
    const u64 f0 = ~rem0 & v0 & above_mask_fn(base0, i);
    const u64 f1 = ~rem1 & v1 & above_mask_fn(base1, i);
    int ni = -1;
    const u64 b0 = __ballot(f0 != 0ULL);
    if (b0) {
      const int w = (int)__builtin_ctzll(b0);
      const u64 fw = (u64)__shfl((long long)f0, w);
      ni = (w << 6) + (int)__builtin_ctzll(fw);
    } else {
      const u64 b1m = __ballot(f1 != 0ULL);
      if (b1m) {
        const int w = (int)__builtin_ctzll(b1m);
        const u64 fw = (u64)__shfl((long long)f1, w);
        ni = ((64 + w) << 6) + (int)__builtin_ctzll(fw);
      }
    }
    i = ni;
  }
#undef GISSUE
}

// ---------------- launch ----------------
extern "C" void kernel_launch(void* const* d_in, const int* in_sizes, int n_in,
                              void* d_out, int out_size, void* d_ws, size_t ws_size,
                              hipStream_t stream) {
  (void)in_sizes; (void)n_in; (void)out_size;
  if (ws_size < BASE_NEEDED) return;
  const bool fast = (ws_size >= FULL_NEEDED);

  const float* x       = (const float*)d_in[0];
  const float* conv_w  = (const float*)d_in[1];
  const float* conv_b  = (const float*)d_in[2];
  const float* loc_w   = (const float*)d_in[3];
  const float* loc_b   = (const float*)d_in[4];
  const float* score_w = (const float*)d_in[5];
  const float* score_b = (const float*)d_in[6];
  const int* p_ih = (const int*)d_in[7];
  const int* p_iw = (const int*)d_in[8];
  const int* p_sc = (const int*)d_in[9];

  float* out0 = (float*)d_out;
  float* out1 = out0 + 589824;
  float* roi  = out1 + 294912;
  float* out3 = roi + 1200;

  char* ws = (char*)d_ws;
  float*     h     = (float*)(ws + OFF_H);
  float4*    boxes = (float4*)(ws + OFF_BOXES);
  u32*       keys  = (u32*)(ws + OFF_KEYS);
  float*     w54   = (float*)(ws + OFF_W54);
  float*     b54   = (float*)(ws + OFF_B54);
  u32*       hist1 = (u32*)(ws + OFF_HIST1);
  u32*       hist2 = (u32*)(ws + OFF_HIST2);
  u32*       ctrl  = (u32*)(ws + OFF_CTRL);
  u64*       cand  = (u64*)(ws + OFF_CAND);
  float4*    sbox  = (float4*)(ws + OFF_SBOX);
  u64*       mask  = (u64*)(ws + OFF_MASK);
  _Float16*  xh    = (_Float16*)(ws + OFF_XH);
  _Float16*  xl    = (_Float16*)(ws + OFF_XL);
  _Float16*  whPK  = (_Float16*)(ws + OFF_WHT);
  _Float16*  wlPK  = (_Float16*)(ws + OFF_WLT);

  AB ab;
  {
    const double ratios[3] = {0.5, 1.0, 2.0};
    const double scales[3] = {8.0, 16.0, 32.0};
    for (int i = 0; i < 3; ++i)
      for (int j = 0; j < 3; ++j) {
        const double hh = 16.0 * scales[j] * sqrt(ratios[i]);
        const double wwv = 16.0 * scales[j] * sqrt(1.0 / ratios[i]);
        const int a = i * 3 + j;
        ab.v[a * 4 + 0] = (float)(8.0 - hh / 2.0);
        ab.v[a * 4 + 1] = (float)(8.0 - wwv / 2.0);
        ab.v[a * 4 + 2] = (float)(8.0 + hh / 2.0);
        ab.v[a * 4 + 3] = (float)(8.0 + wwv / 2.0);
      }
  }

  if (fast) {
    hipLaunchKernelGGL(k_prep, dim3(4928), dim3(256), 0, stream,
                       x, xh, xl, conv_w, whPK, wlPK,
                       hist1, hist2, ctrl, roi, w54, b54, loc_w, loc_b, score_w, score_b);
    hipLaunchKernelGGL(k_conv_pre, dim3(512), dim3(256), 0, stream, xh, xl, whPK, wlPK, conv_b, h);
  } else {
    hipLaunchKernelGGL(k_init, dim3(256), dim3(256), 0, stream,
                       hist1, hist2, ctrl, roi, w54, b54, loc_w, loc_b, score_w, score_b);
    hipLaunchKernelGGL(k_conv_fb, dim3(128, 4), dim3(256), 0, stream, x, conv_w, conv_b, h);
  }
  hipLaunchKernelGGL(k_heads, dim3(1024), dim3(256), 0, stream,
                     h, (const float4*)w54, b54, out0, out1, out3, boxes, keys, hist1,
                     p_ih, p_iw, p_sc, ab);
  hipLaunchKernelGGL(k_findcut, dim3(1), dim3(1024), 0, stream, hist1, ctrl, 0);
  hipLaunchKernelGGL(k_hist2, dim3(576), dim3(256), 0, stream, keys, ctrl, hist2);
  hipLaunchKernelGGL(k_findcut, dim3(1), dim3(1024), 0, stream, hist2, ctrl, 1);
  hipLaunchKernelGGL(k_compact, dim3(576), dim3(256), 0, stream, keys, ctrl, cand);
  hipLaunchKernelGGL(k_rank, dim3(8192), dim3(128), 0, stream, ctrl, cand, boxes, sbox);
  hipLaunchKernelGGL(k_mask, dim3(24, 94), dim3(256), 0, stream, ctrl, sbox, mask);
  hipLaunchKernelGGL(k_greedy, dim3(1), dim3(64), 0, stream, ctrl, (const float*)sbox, mask, roi);
}